// Round 14
// baseline (115.915 us; speedup 1.0000x reference)
//
#include <hip/hip_runtime.h>
#include <hip/hip_bf16.h>

#define GG 16384          // G*G
#define NBAG 16
#define NPT 65536
#define NCELL (NBAG * GG)
#define MAXM NPT
#define ZROW MAXM         // dedicated zero row in feat buffers (sized MAXM+1 rows)

typedef __bf16 bf16x8 __attribute__((ext_vector_type(8)));
typedef float f32x4 __attribute__((ext_vector_type(4)));

// R13 structure (best measured: 105.2µs) with ONE change: 4-wide k_scatter.
// Lessons baked in: no single-address atomics in prep (R8: 40µs; R12 spin:
// 56µs), no launch fusion beyond R5's (every further fusion regressed),
// conv untouched (R6: co-mutation cost 2x via regalloc).

// fused zero: counts (1MB) + fsum (32MB) + pooled (8KB), one launch
__global__ __launch_bounds__(256) void k_zero(float* __restrict__ fsum,
                                              int* __restrict__ counts,
                                              float* __restrict__ pooled) {
  int tid = blockIdx.x * 256 + threadIdx.x;  // grid 2048*256 = 524288
  int4 z = make_int4(0, 0, 0, 0);
#pragma unroll
  for (int i = 0; i < 4; ++i) ((int4*)fsum)[tid + i * 524288] = z;
  if (tid < 65536) ((int4*)counts)[tid] = z;
  if (tid < 512) ((int4*)pooled)[tid] = z;
}

// fused: weight transpose+cast+pre-swizzle (blocks [0,1152)) and point count
__global__ __launch_bounds__(256) void k_setup(const float* __restrict__ W1,
                                               const float* __restrict__ W2,
                                               __hip_bfloat16* __restrict__ Wt1,
                                               __hip_bfloat16* __restrict__ Wt2,
                                               const int* __restrict__ coords,
                                               int* __restrict__ counts) {
  int b = blockIdx.x, t = threadIdx.x;
  if (b < 1152) {
    int id = b * 256 + t;  // < 2*147456
    const float* W = (id < 147456) ? W1 : W2;
    __hip_bfloat16* Wt = (id < 147456) ? Wt1 : Wt2;
    int r = (id < 147456) ? id : id - 147456;
    int k = r >> 14, rem = r & 16383, co = rem >> 7, ci = rem & 127;
    int dst = k * 16384 + co * 128 + (((ci >> 3) ^ (co & 7)) << 3) + (ci & 7);
    Wt[dst] = __float2bfloat16(W[k * 16384 + ci * 128 + co]);
  } else {
    int p = (b - 1152) * 256 + t;
    int bg = p >> 12;
    int q0 = coords[p * 2 + 0] >> 5;
    int q1 = coords[p * 2 + 1] >> 5;
    atomicAdd(&counts[bg * GG + q0 * 128 + q1], 1);
  }
}

__global__ __launch_bounds__(256) void k_s1(const int* __restrict__ counts,
                                            int* __restrict__ blockcnt) {
  __shared__ int red[256];
  int t = threadIdx.x;
  int base = blockIdx.x * 1024 + t * 4;
  int c = 0;
#pragma unroll
  for (int i = 0; i < 4; ++i) c += (counts[base + i] > 0) ? 1 : 0;
  red[t] = c;
  __syncthreads();
  for (int d = 128; d > 0; d >>= 1) {
    if (t < d) red[t] += red[t + d];
    __syncthreads();
  }
  if (t == 0) blockcnt[blockIdx.x] = red[0];
}

__global__ __launch_bounds__(256) void k_s2(const int* __restrict__ blockcnt,
                                            int* __restrict__ blockoff,
                                            int* __restrict__ dM,
                                            int* __restrict__ npts) {
  __shared__ int s[256];
  int t = threadIdx.x;
  int v = blockcnt[t];
  s[t] = v;
  __syncthreads();
  for (int d = 1; d < 256; d <<= 1) {
    int x = (t >= d) ? s[t - d] : 0;
    __syncthreads();
    s[t] += x;
    __syncthreads();
  }
  blockoff[t] = s[t] - v;
  if (t == 255) *dM = s[255];
  if (t < NBAG) {
    int sum = 0;
    for (int i = 0; i < 16; ++i) sum += blockcnt[t * 16 + i];
    npts[t] = sum;
  }
}

__global__ __launch_bounds__(256) void k_s3(const int* __restrict__ counts,
                                            const int* __restrict__ blockoff,
                                            int* __restrict__ cellidx,
                                            int* __restrict__ cell_of_idx) {
  __shared__ int s[256];
  int t = threadIdx.x;
  int base = blockIdx.x * 1024 + t * 4;
  int occ[4];
  int c = 0;
#pragma unroll
  for (int i = 0; i < 4; ++i) {
    occ[i] = counts[base + i] > 0;
    c += occ[i];
  }
  s[t] = c;
  __syncthreads();
  for (int d = 1; d < 256; d <<= 1) {
    int x = (t >= d) ? s[t - d] : 0;
    __syncthreads();
    s[t] += x;
    __syncthreads();
  }
  int pos = blockoff[blockIdx.x] + s[t] - c;
#pragma unroll
  for (int i = 0; i < 4; ++i) {
    if (occ[i]) {
      cellidx[base + i] = pos;
      cell_of_idx[pos] = base + i;
      pos++;
    } else {
      cellidx[base + i] = -1;
    }
  }
}

// 4-wide scatter (R14: only change vs R13): 32 threads/point, float4 read,
// 8B bf16 store for count==1 cells (≈88%); else 4 float atomics into fsum.
__global__ __launch_bounds__(256) void k_scatter(const float* __restrict__ x,
                                                 const int* __restrict__ coords,
                                                 const int* __restrict__ cellidx,
                                                 const int* __restrict__ counts,
                                                 float* __restrict__ fsum,
                                                 __hip_bfloat16* __restrict__ feat0) {
  int gid = blockIdx.x * 256 + threadIdx.x;  // grid 8192*256 = 2M
  int p = gid >> 5, c4 = gid & 31;
  int b = p >> 12;
  int q0 = coords[p * 2 + 0] >> 5;
  int q1 = coords[p * 2 + 1] >> 5;
  int cell = b * GG + q0 * 128 + q1;
  int idx = cellidx[cell];
  float4 v = ((const float4*)x)[(size_t)p * 32 + c4];
  if (counts[cell] == 1) {
    __align__(8) __hip_bfloat16 h[4];
    h[0] = __float2bfloat16(v.x);
    h[1] = __float2bfloat16(v.y);
    h[2] = __float2bfloat16(v.z);
    h[3] = __float2bfloat16(v.w);
    *(int2*)(feat0 + (size_t)idx * 128 + c4 * 4) = *(const int2*)h;
  } else {
    float* dst = fsum + (size_t)idx * 128 + c4 * 4;
    atomicAdd(dst + 0, v.x);
    atomicAdd(dst + 1, v.y);
    atomicAdd(dst + 2, v.z);
    atomicAdd(dst + 3, v.w);
  }
}

// fused: average+cast for count>1 cells + ZROW zeroing (blocks [0,4097))
// and nbr table (blocks [4097,4353))
__global__ __launch_bounds__(256) void k_prep(const float* __restrict__ fsum,
                                              const int* __restrict__ counts,
                                              const int* __restrict__ cell_of_idx,
                                              const int* __restrict__ cellidx,
                                              const int* __restrict__ dM,
                                              __hip_bfloat16* __restrict__ feat0,
                                              __hip_bfloat16* __restrict__ feat1,
                                              int* __restrict__ nbrt) {
  int t = threadIdx.x;
  if (blockIdx.x < 4097) {
    int gid = blockIdx.x * 256 + t;
    int cell = gid >> 4, i = gid & 15;
    int M = *dM;
    if (cell >= M) {
      if (cell == M) {
        *(int4*)((char*)(feat0 + (size_t)ZROW * 128) + i * 16) = make_int4(0, 0, 0, 0);
      } else if (cell == M + 1) {
        *(int4*)((char*)(feat1 + (size_t)ZROW * 128) + i * 16) = make_int4(0, 0, 0, 0);
      }
      return;
    }
    int cnt = counts[cell_of_idx[cell]];
    if (cnt == 1) return;  // already written by k_scatter
    float inv = 1.0f / (float)cnt;
    const float4* src = (const float4*)fsum + (size_t)cell * 32 + i * 2;
    float4 v0 = src[0], v1 = src[1];
    __align__(16) __hip_bfloat16 h[8];
    h[0] = __float2bfloat16(v0.x * inv);
    h[1] = __float2bfloat16(v0.y * inv);
    h[2] = __float2bfloat16(v0.z * inv);
    h[3] = __float2bfloat16(v0.w * inv);
    h[4] = __float2bfloat16(v1.x * inv);
    h[5] = __float2bfloat16(v1.y * inv);
    h[6] = __float2bfloat16(v1.z * inv);
    h[7] = __float2bfloat16(v1.w * inv);
    *(int4*)(feat0 + (size_t)cell * 128 + i * 8) = *(const int4*)h;
  } else {
    int idx = (blockIdx.x - 4097) * 256 + t;
    if (idx >= MAXM) return;
    if (idx >= *dM) {
#pragma unroll
      for (int j = 0; j < 9; ++j) nbrt[j * MAXM + idx] = ZROW;
      return;
    }
    int cell = cell_of_idx[idx];
    int b = cell >> 14, ij = cell & 16383;
    int i = ij >> 7, j = ij & 127;
#pragma unroll
    for (int dh = 0; dh < 3; ++dh)
#pragma unroll
      for (int dw = 0; dw < 3; ++dw) {
        int ni = i + dh - 1, nj = j + dw - 1;
        int v = -1;
        if (ni >= 0 && ni < 128 && nj >= 0 && nj < 128)
          v = cellidx[b * GG + ni * 128 + nj];
        nbrt[(dh * 3 + dw) * MAXM + idx] = (v < 0) ? ZROW : v;
      }
  }
}

// MFMA gathered sparse conv — R10 schedule verbatim (best measured).
// Counted vmcnt(8) + raw barrier at tap top; stage/A prefetch after barrier.
template <bool POOL>
__global__ __launch_bounds__(256, 2) void k_conv(
    const __hip_bfloat16* __restrict__ fin,   // [MAXM+1][128]
    const __hip_bfloat16* __restrict__ Wt,    // [9][128][128] pre-swizzled
    __hip_bfloat16* __restrict__ fout,
    float* __restrict__ pooled,
    const int* __restrict__ nbrt,             // [9][MAXM]
    const int* __restrict__ cell_of_idx,
    const int* __restrict__ dM) {
  __shared__ __align__(16) char smem[65536];
  const int M = *dM;
  // bijective chunked XCD swizzle (gridDim.x = 512, divisible by 8)
  const int lb = (blockIdx.x & 7) * (gridDim.x >> 3) + (blockIdx.x >> 3);
  const int base = lb * 128;
  if (base >= M) return;
  const int t = threadIdx.x;
  const int w = t >> 6;
  const int l = t & 63;
  const int u = l >> 4;
  const int c = l & 15;
  const int wrow = base + w * 32;

  auto stageW = [&](int k, int b) {
    const __hip_bfloat16* gw = Wt + (size_t)k * 16384 + w * 4096;
    char* lbuf = smem + b * 32768 + w * 8192;
#pragma unroll
    for (int j = 0; j < 8; ++j) {
      __builtin_amdgcn_global_load_lds(
          (const __attribute__((address_space(1))) void*)(gw + j * 512 + l * 8),
          (__attribute__((address_space(3))) void*)(lbuf + j * 1024), 16, 0, 0);
    }
  };
  auto loadA = [&](int nb, int kb) {
    return *(const bf16x8*)((const char*)fin + (size_t)nb * 256 + kb * 64 + u * 16);
  };

  f32x4 acc[2][8];
#pragma unroll
  for (int mf = 0; mf < 2; ++mf)
#pragma unroll
    for (int nf = 0; nf < 8; ++nf) acc[mf][nf] = f32x4{0.f, 0.f, 0.f, 0.f};

  bf16x8 aP[2][2][4];  // [parity][mf][kb]
  int nb_c[2], nb_n[2];
  nb_c[0] = nbrt[0 * MAXM + wrow + c];
  nb_c[1] = nbrt[0 * MAXM + wrow + 16 + c];
  nb_n[0] = nbrt[1 * MAXM + wrow + c];
  nb_n[1] = nbrt[1 * MAXM + wrow + 16 + c];
  stageW(0, 0);                         // oldest-8 vm ops
  __builtin_amdgcn_sched_barrier(0);    // keep stage ops oldest for vmcnt(8)
#pragma unroll
  for (int mf = 0; mf < 2; ++mf)
#pragma unroll
    for (int kb = 0; kb < 4; ++kb) aP[0][mf][kb] = loadA(nb_c[mf], kb);

#pragma unroll
  for (int k = 0; k < 9; ++k) {
    const int cp = k & 1, np = cp ^ 1;  // constants after full unroll
    asm volatile("s_waitcnt vmcnt(8)" ::: "memory");  // W(k) landed
    __builtin_amdgcn_s_barrier();       // all waves: W(k) in LDS, tap k-1 reads done
    if (k < 8) {
      stageW(k + 1, (k + 1) & 1);       // overwrites buf last read at tap k-1
      __builtin_amdgcn_sched_barrier(0);
#pragma unroll
      for (int mf = 0; mf < 2; ++mf)
#pragma unroll
        for (int kb = 0; kb < 4; ++kb) aP[np][mf][kb] = loadA(nb_n[mf], kb);
    }
    if (k < 7) {
      nb_n[0] = nbrt[(k + 2) * MAXM + wrow + c];
      nb_n[1] = nbrt[(k + 2) * MAXM + wrow + 16 + c];
    }
    const char* wb = smem + (k & 1) * 32768;
    __builtin_amdgcn_s_setprio(1);
#pragma unroll
    for (int kb = 0; kb < 4; ++kb) {
      bf16x8 wf[8];
#pragma unroll
      for (int nf = 0; nf < 8; ++nf) {
        int co = nf * 16 + c;
        int ch = (kb * 4 + u) ^ (c & 7);
        wf[nf] = *(const bf16x8*)(wb + co * 256 + ch * 16);
      }
#pragma unroll
      for (int mf = 0; mf < 2; ++mf)
#pragma unroll
        for (int nf = 0; nf < 8; ++nf)
          acc[mf][nf] = __builtin_amdgcn_mfma_f32_16x16x32_bf16(
              aP[cp][mf][kb], wf[nf], acc[mf][nf], 0, 0, 0);
    }
    __builtin_amdgcn_s_setprio(0);
  }
  __syncthreads();  // all waves done reading buf before epilogue smem reuse

  if (!POOL) {
    char* ep = smem + w * 8704;  // 32 rows x 272B (16B pad breaks conflicts)
#pragma unroll
    for (int mf = 0; mf < 2; ++mf)
#pragma unroll
      for (int nf = 0; nf < 8; ++nf)
#pragma unroll
        for (int i = 0; i < 4; ++i) {
          int rl = mf * 16 + u * 4 + i;
          int col = nf * 16 + c;
          *(__hip_bfloat16*)(ep + rl * 272 + col * 2) =
              __float2bfloat16(fmaxf(acc[mf][nf][i], 0.f));
        }
    __syncthreads();
#pragma unroll
    for (int j = 0; j < 8; ++j) {
      int rl = j * 4 + u;
      int grow = wrow + rl;
      int4 v = *(const int4*)(ep + rl * 272 + c * 16);
      if (grow < M)
        *(int4*)((char*)fout + (size_t)grow * 256 + c * 16) = v;
    }
  } else {
    if (wrow < M) {
      int b0 = cell_of_idx[wrow] >> 14;
      int lastr = min(wrow + 31, M - 1);
      int b1 = cell_of_idx[lastr] >> 14;
      float p0[8] = {0.f, 0.f, 0.f, 0.f, 0.f, 0.f, 0.f, 0.f};
      float p1[8] = {0.f, 0.f, 0.f, 0.f, 0.f, 0.f, 0.f, 0.f};
#pragma unroll
      for (int mf = 0; mf < 2; ++mf)
#pragma unroll
        for (int i = 0; i < 4; ++i) {
          int r = wrow + mf * 16 + u * 4 + i;
          int bg = (r < M) ? (cell_of_idx[r] >> 14) : -1;
#pragma unroll
          for (int nf = 0; nf < 8; ++nf) {
            float v = fmaxf(acc[mf][nf][i], 0.f);
            if (bg == b0) p0[nf] += v;
            else if (bg == b1) p1[nf] += v;
          }
        }
      bool two = (b1 != b0);
#pragma unroll
      for (int nf = 0; nf < 8; ++nf) {
        p0[nf] += __shfl_xor(p0[nf], 16);
        p0[nf] += __shfl_xor(p0[nf], 32);
        p1[nf] += __shfl_xor(p1[nf], 16);
        p1[nf] += __shfl_xor(p1[nf], 32);
      }
      if (u == 0) {
#pragma unroll
        for (int nf = 0; nf < 8; ++nf) {
          atomicAdd(&pooled[b0 * 128 + nf * 16 + c], p0[nf]);
          if (two) atomicAdd(&pooled[b1 * 128 + nf * 16 + c], p1[nf]);
        }
      }
    }
  }
}

__global__ __launch_bounds__(256) void k_logits(const float* __restrict__ pooled,
                                                const int* __restrict__ npts,
                                                const float* __restrict__ Wc,
                                                const float* __restrict__ bc,
                                                float* __restrict__ out) {
  int t = threadIdx.x;
  if (t >= 160) return;
  int b = t / 10, n = t % 10;
  float inv = 1.0f / (float)npts[b];
  float s = 0.f;
  for (int c = 0; c < 128; ++c) s += pooled[b * 128 + c] * Wc[c * 10 + n];
  out[t] = s * inv + bc[n];
}

extern "C" void kernel_launch(void* const* d_in, const int* in_sizes, int n_in,
                              void* d_out, int out_size, void* d_ws, size_t ws_size,
                              hipStream_t stream) {
  const float* x = (const float*)d_in[0];
  const int* coords = (const int*)d_in[1];
  const float* W1 = (const float*)d_in[2];
  const float* W2 = (const float*)d_in[3];
  const float* Wc = (const float*)d_in[4];
  const float* bc = (const float*)d_in[5];
  float* out = (float*)d_out;

  char* ws = (char*)d_ws;
  size_t off = 0;
  auto take = [&](size_t bytes) {
    void* p = ws + off;
    off += (bytes + 255) & ~(size_t)255;
    return p;
  };
  int* counts      = (int*)take((size_t)NCELL * 4);
  int* cellidx     = (int*)take((size_t)NCELL * 4);
  int* cell_of_idx = (int*)take((size_t)MAXM * 4);
  int* blockcnt    = (int*)take(256 * 4);
  int* blockoff    = (int*)take(256 * 4);
  int* dM          = (int*)take(4);
  int* npts        = (int*)take(64);
  int* nbrt        = (int*)take((size_t)9 * MAXM * 4);
  float* fsum      = (float*)take((size_t)MAXM * 128 * 4);
  __hip_bfloat16* feat0 = (__hip_bfloat16*)take((size_t)(MAXM + 1) * 128 * 2);
  __hip_bfloat16* feat1 = (__hip_bfloat16*)take((size_t)(MAXM + 1) * 128 * 2);
  __hip_bfloat16* Wt1   = (__hip_bfloat16*)take((size_t)9 * 128 * 128 * 2);
  __hip_bfloat16* Wt2   = (__hip_bfloat16*)take((size_t)9 * 128 * 128 * 2);
  float* pooled    = (float*)take(16 * 128 * 4);

  k_zero<<<2048, 256, 0, stream>>>(fsum, counts, pooled);
  k_setup<<<1408, 256, 0, stream>>>(W1, W2, Wt1, Wt2, coords, counts);
  k_s1<<<256, 256, 0, stream>>>(counts, blockcnt);
  k_s2<<<1, 256, 0, stream>>>(blockcnt, blockoff, dM, npts);
  k_s3<<<256, 256, 0, stream>>>(counts, blockoff, cellidx, cell_of_idx);
  k_scatter<<<NPT * 32 / 256, 256, 0, stream>>>(x, coords, cellidx, counts, fsum, feat0);
  k_prep<<<4353, 256, 0, stream>>>(fsum, counts, cell_of_idx, cellidx, dM, feat0, feat1, nbrt);
  k_conv<false><<<MAXM / 128, 256, 0, stream>>>(feat0, Wt1, feat1, nullptr, nbrt,
                                                cell_of_idx, dM);
  k_conv<true><<<MAXM / 128, 256, 0, stream>>>(feat1, Wt2, nullptr, pooled, nbrt,
                                               cell_of_idx, dM);
  k_logits<<<1, 256, 0, stream>>>(pooled, npts, Wc, bc, out);
}

// Round 15
// 104.161 us; speedup vs baseline: 1.1128x; 1.1128x over previous
//
#include <hip/hip_runtime.h>
#include <hip/hip_bf16.h>

#define GG 16384          // G*G
#define NBAG 16
#define NPT 65536
#define NCELL (NBAG * GG)
#define MAXM NPT
#define ZROW MAXM         // dedicated zero row in feat buffers (sized MAXM+1 rows)

typedef __bf16 bf16x8 __attribute__((ext_vector_type(8)));
typedef float f32x4 __attribute__((ext_vector_type(4)));

// R13 configuration byte-for-byte (best measured: 105.2µs). Session lessons:
// - scalar scatter > 4-wide scatter (R14: wave-uniform branch + broadcast
//   index loads beat 4x fewer instructions; +10.7µs regression)
// - no single-address atomics in prep (R8 mlist: 40µs; R12 spin-bar: 56µs)
// - no launch fusion beyond R5's (R6/R12 fusions all regressed)
// - conv: R10 counted-vmcnt schedule, never co-mutate (R6 regalloc 2x)

// fused zero: counts (1MB) + fsum (32MB) + pooled (8KB), one launch
__global__ __launch_bounds__(256) void k_zero(float* __restrict__ fsum,
                                              int* __restrict__ counts,
                                              float* __restrict__ pooled) {
  int tid = blockIdx.x * 256 + threadIdx.x;  // grid 2048*256 = 524288
  int4 z = make_int4(0, 0, 0, 0);
#pragma unroll
  for (int i = 0; i < 4; ++i) ((int4*)fsum)[tid + i * 524288] = z;
  if (tid < 65536) ((int4*)counts)[tid] = z;
  if (tid < 512) ((int4*)pooled)[tid] = z;
}

// fused: weight transpose+cast+pre-swizzle (blocks [0,1152)) and point count
__global__ __launch_bounds__(256) void k_setup(const float* __restrict__ W1,
                                               const float* __restrict__ W2,
                                               __hip_bfloat16* __restrict__ Wt1,
                                               __hip_bfloat16* __restrict__ Wt2,
                                               const int* __restrict__ coords,
                                               int* __restrict__ counts) {
  int b = blockIdx.x, t = threadIdx.x;
  if (b < 1152) {
    int id = b * 256 + t;  // < 2*147456
    const float* W = (id < 147456) ? W1 : W2;
    __hip_bfloat16* Wt = (id < 147456) ? Wt1 : Wt2;
    int r = (id < 147456) ? id : id - 147456;
    int k = r >> 14, rem = r & 16383, co = rem >> 7, ci = rem & 127;
    int dst = k * 16384 + co * 128 + (((ci >> 3) ^ (co & 7)) << 3) + (ci & 7);
    Wt[dst] = __float2bfloat16(W[k * 16384 + ci * 128 + co]);
  } else {
    int p = (b - 1152) * 256 + t;
    int bg = p >> 12;
    int q0 = coords[p * 2 + 0] >> 5;
    int q1 = coords[p * 2 + 1] >> 5;
    atomicAdd(&counts[bg * GG + q0 * 128 + q1], 1);
  }
}

__global__ __launch_bounds__(256) void k_s1(const int* __restrict__ counts,
                                            int* __restrict__ blockcnt) {
  __shared__ int red[256];
  int t = threadIdx.x;
  int base = blockIdx.x * 1024 + t * 4;
  int c = 0;
#pragma unroll
  for (int i = 0; i < 4; ++i) c += (counts[base + i] > 0) ? 1 : 0;
  red[t] = c;
  __syncthreads();
  for (int d = 128; d > 0; d >>= 1) {
    if (t < d) red[t] += red[t + d];
    __syncthreads();
  }
  if (t == 0) blockcnt[blockIdx.x] = red[0];
}

__global__ __launch_bounds__(256) void k_s2(const int* __restrict__ blockcnt,
                                            int* __restrict__ blockoff,
                                            int* __restrict__ dM,
                                            int* __restrict__ npts) {
  __shared__ int s[256];
  int t = threadIdx.x;
  int v = blockcnt[t];
  s[t] = v;
  __syncthreads();
  for (int d = 1; d < 256; d <<= 1) {
    int x = (t >= d) ? s[t - d] : 0;
    __syncthreads();
    s[t] += x;
    __syncthreads();
  }
  blockoff[t] = s[t] - v;
  if (t == 255) *dM = s[255];
  if (t < NBAG) {
    int sum = 0;
    for (int i = 0; i < 16; ++i) sum += blockcnt[t * 16 + i];
    npts[t] = sum;
  }
}

__global__ __launch_bounds__(256) void k_s3(const int* __restrict__ counts,
                                            const int* __restrict__ blockoff,
                                            int* __restrict__ cellidx,
                                            int* __restrict__ cell_of_idx) {
  __shared__ int s[256];
  int t = threadIdx.x;
  int base = blockIdx.x * 1024 + t * 4;
  int occ[4];
  int c = 0;
#pragma unroll
  for (int i = 0; i < 4; ++i) {
    occ[i] = counts[base + i] > 0;
    c += occ[i];
  }
  s[t] = c;
  __syncthreads();
  for (int d = 1; d < 256; d <<= 1) {
    int x = (t >= d) ? s[t - d] : 0;
    __syncthreads();
    s[t] += x;
    __syncthreads();
  }
  int pos = blockoff[blockIdx.x] + s[t] - c;
#pragma unroll
  for (int i = 0; i < 4; ++i) {
    if (occ[i]) {
      cellidx[base + i] = pos;
      cell_of_idx[pos] = base + i;
      pos++;
    } else {
      cellidx[base + i] = -1;
    }
  }
}

// scalar scatter (R14 lesson: 128 threads/point -> wave-uniform branch,
// broadcast index loads; beats the 4-wide form by ~10µs).
// count==1 cells (≈88%) write bf16 feat0 directly; else atomic fsum.
__global__ __launch_bounds__(256) void k_scatter(const float* __restrict__ x,
                                                 const int* __restrict__ coords,
                                                 const int* __restrict__ cellidx,
                                                 const int* __restrict__ counts,
                                                 float* __restrict__ fsum,
                                                 __hip_bfloat16* __restrict__ feat0) {
  int gid = blockIdx.x * 256 + threadIdx.x;
  int p = gid >> 7, c = gid & 127;
  int b = p >> 12;
  int q0 = coords[p * 2 + 0] >> 5;
  int q1 = coords[p * 2 + 1] >> 5;
  int cell = b * GG + q0 * 128 + q1;
  int idx = cellidx[cell];
  float v = x[(size_t)p * 128 + c];
  if (counts[cell] == 1) {
    feat0[(size_t)idx * 128 + c] = __float2bfloat16(v);
  } else {
    atomicAdd(&fsum[(size_t)idx * 128 + c], v);
  }
}

// fused: average+cast for count>1 cells + ZROW zeroing (blocks [0,4097))
// and nbr table (blocks [4097,4353))
__global__ __launch_bounds__(256) void k_prep(const float* __restrict__ fsum,
                                              const int* __restrict__ counts,
                                              const int* __restrict__ cell_of_idx,
                                              const int* __restrict__ cellidx,
                                              const int* __restrict__ dM,
                                              __hip_bfloat16* __restrict__ feat0,
                                              __hip_bfloat16* __restrict__ feat1,
                                              int* __restrict__ nbrt) {
  int t = threadIdx.x;
  if (blockIdx.x < 4097) {
    int gid = blockIdx.x * 256 + t;
    int cell = gid >> 4, i = gid & 15;
    int M = *dM;
    if (cell >= M) {
      if (cell == M) {
        *(int4*)((char*)(feat0 + (size_t)ZROW * 128) + i * 16) = make_int4(0, 0, 0, 0);
      } else if (cell == M + 1) {
        *(int4*)((char*)(feat1 + (size_t)ZROW * 128) + i * 16) = make_int4(0, 0, 0, 0);
      }
      return;
    }
    int cnt = counts[cell_of_idx[cell]];
    if (cnt == 1) return;  // already written by k_scatter
    float inv = 1.0f / (float)cnt;
    const float4* src = (const float4*)fsum + (size_t)cell * 32 + i * 2;
    float4 v0 = src[0], v1 = src[1];
    __align__(16) __hip_bfloat16 h[8];
    h[0] = __float2bfloat16(v0.x * inv);
    h[1] = __float2bfloat16(v0.y * inv);
    h[2] = __float2bfloat16(v0.z * inv);
    h[3] = __float2bfloat16(v0.w * inv);
    h[4] = __float2bfloat16(v1.x * inv);
    h[5] = __float2bfloat16(v1.y * inv);
    h[6] = __float2bfloat16(v1.z * inv);
    h[7] = __float2bfloat16(v1.w * inv);
    *(int4*)(feat0 + (size_t)cell * 128 + i * 8) = *(const int4*)h;
  } else {
    int idx = (blockIdx.x - 4097) * 256 + t;
    if (idx >= MAXM) return;
    if (idx >= *dM) {
#pragma unroll
      for (int j = 0; j < 9; ++j) nbrt[j * MAXM + idx] = ZROW;
      return;
    }
    int cell = cell_of_idx[idx];
    int b = cell >> 14, ij = cell & 16383;
    int i = ij >> 7, j = ij & 127;
#pragma unroll
    for (int dh = 0; dh < 3; ++dh)
#pragma unroll
      for (int dw = 0; dw < 3; ++dw) {
        int ni = i + dh - 1, nj = j + dw - 1;
        int v = -1;
        if (ni >= 0 && ni < 128 && nj >= 0 && nj < 128)
          v = cellidx[b * GG + ni * 128 + nj];
        nbrt[(dh * 3 + dw) * MAXM + idx] = (v < 0) ? ZROW : v;
      }
  }
}

// MFMA gathered sparse conv — R10 schedule verbatim (best measured).
// Counted vmcnt(8) + raw barrier at tap top; stage/A prefetch after barrier.
template <bool POOL>
__global__ __launch_bounds__(256, 2) void k_conv(
    const __hip_bfloat16* __restrict__ fin,   // [MAXM+1][128]
    const __hip_bfloat16* __restrict__ Wt,    // [9][128][128] pre-swizzled
    __hip_bfloat16* __restrict__ fout,
    float* __restrict__ pooled,
    const int* __restrict__ nbrt,             // [9][MAXM]
    const int* __restrict__ cell_of_idx,
    const int* __restrict__ dM) {
  __shared__ __align__(16) char smem[65536];
  const int M = *dM;
  // bijective chunked XCD swizzle (gridDim.x = 512, divisible by 8)
  const int lb = (blockIdx.x & 7) * (gridDim.x >> 3) + (blockIdx.x >> 3);
  const int base = lb * 128;
  if (base >= M) return;
  const int t = threadIdx.x;
  const int w = t >> 6;
  const int l = t & 63;
  const int u = l >> 4;
  const int c = l & 15;
  const int wrow = base + w * 32;

  auto stageW = [&](int k, int b) {
    const __hip_bfloat16* gw = Wt + (size_t)k * 16384 + w * 4096;
    char* lbuf = smem + b * 32768 + w * 8192;
#pragma unroll
    for (int j = 0; j < 8; ++j) {
      __builtin_amdgcn_global_load_lds(
          (const __attribute__((address_space(1))) void*)(gw + j * 512 + l * 8),
          (__attribute__((address_space(3))) void*)(lbuf + j * 1024), 16, 0, 0);
    }
  };
  auto loadA = [&](int nb, int kb) {
    return *(const bf16x8*)((const char*)fin + (size_t)nb * 256 + kb * 64 + u * 16);
  };

  f32x4 acc[2][8];
#pragma unroll
  for (int mf = 0; mf < 2; ++mf)
#pragma unroll
    for (int nf = 0; nf < 8; ++nf) acc[mf][nf] = f32x4{0.f, 0.f, 0.f, 0.f};

  bf16x8 aP[2][2][4];  // [parity][mf][kb]
  int nb_c[2], nb_n[2];
  nb_c[0] = nbrt[0 * MAXM + wrow + c];
  nb_c[1] = nbrt[0 * MAXM + wrow + 16 + c];
  nb_n[0] = nbrt[1 * MAXM + wrow + c];
  nb_n[1] = nbrt[1 * MAXM + wrow + 16 + c];
  stageW(0, 0);                         // oldest-8 vm ops
  __builtin_amdgcn_sched_barrier(0);    // keep stage ops oldest for vmcnt(8)
#pragma unroll
  for (int mf = 0; mf < 2; ++mf)
#pragma unroll
    for (int kb = 0; kb < 4; ++kb) aP[0][mf][kb] = loadA(nb_c[mf], kb);

#pragma unroll
  for (int k = 0; k < 9; ++k) {
    const int cp = k & 1, np = cp ^ 1;  // constants after full unroll
    asm volatile("s_waitcnt vmcnt(8)" ::: "memory");  // W(k) landed
    __builtin_amdgcn_s_barrier();       // all waves: W(k) in LDS, tap k-1 reads done
    if (k < 8) {
      stageW(k + 1, (k + 1) & 1);       // overwrites buf last read at tap k-1
      __builtin_amdgcn_sched_barrier(0);
#pragma unroll
      for (int mf = 0; mf < 2; ++mf)
#pragma unroll
        for (int kb = 0; kb < 4; ++kb) aP[np][mf][kb] = loadA(nb_n[mf], kb);
    }
    if (k < 7) {
      nb_n[0] = nbrt[(k + 2) * MAXM + wrow + c];
      nb_n[1] = nbrt[(k + 2) * MAXM + wrow + 16 + c];
    }
    const char* wb = smem + (k & 1) * 32768;
    __builtin_amdgcn_s_setprio(1);
#pragma unroll
    for (int kb = 0; kb < 4; ++kb) {
      bf16x8 wf[8];
#pragma unroll
      for (int nf = 0; nf < 8; ++nf) {
        int co = nf * 16 + c;
        int ch = (kb * 4 + u) ^ (c & 7);
        wf[nf] = *(const bf16x8*)(wb + co * 256 + ch * 16);
      }
#pragma unroll
      for (int mf = 0; mf < 2; ++mf)
#pragma unroll
        for (int nf = 0; nf < 8; ++nf)
          acc[mf][nf] = __builtin_amdgcn_mfma_f32_16x16x32_bf16(
              aP[cp][mf][kb], wf[nf], acc[mf][nf], 0, 0, 0);
    }
    __builtin_amdgcn_s_setprio(0);
  }
  __syncthreads();  // all waves done reading buf before epilogue smem reuse

  if (!POOL) {
    char* ep = smem + w * 8704;  // 32 rows x 272B (16B pad breaks conflicts)
#pragma unroll
    for (int mf = 0; mf < 2; ++mf)
#pragma unroll
      for (int nf = 0; nf < 8; ++nf)
#pragma unroll
        for (int i = 0; i < 4; ++i) {
          int rl = mf * 16 + u * 4 + i;
          int col = nf * 16 + c;
          *(__hip_bfloat16*)(ep + rl * 272 + col * 2) =
              __float2bfloat16(fmaxf(acc[mf][nf][i], 0.f));
        }
    __syncthreads();
#pragma unroll
    for (int j = 0; j < 8; ++j) {
      int rl = j * 4 + u;
      int grow = wrow + rl;
      int4 v = *(const int4*)(ep + rl * 272 + c * 16);
      if (grow < M)
        *(int4*)((char*)fout + (size_t)grow * 256 + c * 16) = v;
    }
  } else {
    if (wrow < M) {
      int b0 = cell_of_idx[wrow] >> 14;
      int lastr = min(wrow + 31, M - 1);
      int b1 = cell_of_idx[lastr] >> 14;
      float p0[8] = {0.f, 0.f, 0.f, 0.f, 0.f, 0.f, 0.f, 0.f};
      float p1[8] = {0.f, 0.f, 0.f, 0.f, 0.f, 0.f, 0.f, 0.f};
#pragma unroll
      for (int mf = 0; mf < 2; ++mf)
#pragma unroll
        for (int i = 0; i < 4; ++i) {
          int r = wrow + mf * 16 + u * 4 + i;
          int bg = (r < M) ? (cell_of_idx[r] >> 14) : -1;
#pragma unroll
          for (int nf = 0; nf < 8; ++nf) {
            float v = fmaxf(acc[mf][nf][i], 0.f);
            if (bg == b0) p0[nf] += v;
            else if (bg == b1) p1[nf] += v;
          }
        }
      bool two = (b1 != b0);
#pragma unroll
      for (int nf = 0; nf < 8; ++nf) {
        p0[nf] += __shfl_xor(p0[nf], 16);
        p0[nf] += __shfl_xor(p0[nf], 32);
        p1[nf] += __shfl_xor(p1[nf], 16);
        p1[nf] += __shfl_xor(p1[nf], 32);
      }
      if (u == 0) {
#pragma unroll
        for (int nf = 0; nf < 8; ++nf) {
          atomicAdd(&pooled[b0 * 128 + nf * 16 + c], p0[nf]);
          if (two) atomicAdd(&pooled[b1 * 128 + nf * 16 + c], p1[nf]);
        }
      }
    }
  }
}

__global__ __launch_bounds__(256) void k_logits(const float* __restrict__ pooled,
                                                const int* __restrict__ npts,
                                                const float* __restrict__ Wc,
                                                const float* __restrict__ bc,
                                                float* __restrict__ out) {
  int t = threadIdx.x;
  if (t >= 160) return;
  int b = t / 10, n = t % 10;
  float inv = 1.0f / (float)npts[b];
  float s = 0.f;
  for (int c = 0; c < 128; ++c) s += pooled[b * 128 + c] * Wc[c * 10 + n];
  out[t] = s * inv + bc[n];
}

extern "C" void kernel_launch(void* const* d_in, const int* in_sizes, int n_in,
                              void* d_out, int out_size, void* d_ws, size_t ws_size,
                              hipStream_t stream) {
  const float* x = (const float*)d_in[0];
  const int* coords = (const int*)d_in[1];
  const float* W1 = (const float*)d_in[2];
  const float* W2 = (const float*)d_in[3];
  const float* Wc = (const float*)d_in[4];
  const float* bc = (const float*)d_in[5];
  float* out = (float*)d_out;

  char* ws = (char*)d_ws;
  size_t off = 0;
  auto take = [&](size_t bytes) {
    void* p = ws + off;
    off += (bytes + 255) & ~(size_t)255;
    return p;
  };
  int* counts      = (int*)take((size_t)NCELL * 4);
  int* cellidx     = (int*)take((size_t)NCELL * 4);
  int* cell_of_idx = (int*)take((size_t)MAXM * 4);
  int* blockcnt    = (int*)take(256 * 4);
  int* blockoff    = (int*)take(256 * 4);
  int* dM          = (int*)take(4);
  int* npts        = (int*)take(64);
  int* nbrt        = (int*)take((size_t)9 * MAXM * 4);
  float* fsum      = (float*)take((size_t)MAXM * 128 * 4);
  __hip_bfloat16* feat0 = (__hip_bfloat16*)take((size_t)(MAXM + 1) * 128 * 2);
  __hip_bfloat16* feat1 = (__hip_bfloat16*)take((size_t)(MAXM + 1) * 128 * 2);
  __hip_bfloat16* Wt1   = (__hip_bfloat16*)take((size_t)9 * 128 * 128 * 2);
  __hip_bfloat16* Wt2   = (__hip_bfloat16*)take((size_t)9 * 128 * 128 * 2);
  float* pooled    = (float*)take(16 * 128 * 4);

  k_zero<<<2048, 256, 0, stream>>>(fsum, counts, pooled);
  k_setup<<<1408, 256, 0, stream>>>(W1, W2, Wt1, Wt2, coords, counts);
  k_s1<<<256, 256, 0, stream>>>(counts, blockcnt);
  k_s2<<<1, 256, 0, stream>>>(blockcnt, blockoff, dM, npts);
  k_s3<<<256, 256, 0, stream>>>(counts, blockoff, cellidx, cell_of_idx);
  k_scatter<<<NPT * 128 / 256, 256, 0, stream>>>(x, coords, cellidx, counts, fsum, feat0);
  k_prep<<<4353, 256, 0, stream>>>(fsum, counts, cell_of_idx, cellidx, dM, feat0, feat1, nbrt);
  k_conv<false><<<MAXM / 128, 256, 0, stream>>>(feat0, Wt1, feat1, nullptr, nbrt,
                                                cell_of_idx, dM);
  k_conv<true><<<MAXM / 128, 256, 0, stream>>>(feat1, Wt2, nullptr, pooled, nbrt,
                                               cell_of_idx, dM);
  k_logits<<<1, 256, 0, stream>>>(pooled, npts, Wc, bc, out);
}